// Round 5
// baseline (1010.834 us; speedup 1.0000x reference)
//
#include <hip/hip_runtime.h>

// Problem constants
#define BB   512
#define CC   22
#define TT   1000
#define HH   64
#define NCLS 4
#define TC   250          // time chunk staged in LDS
#define NCHUNK (TT / TC)

typedef _Float16 f16;
typedef __attribute__((ext_vector_type(2))) _Float16 h2;

union PU { unsigned u; h2 h; };

__device__ __forceinline__ float sigm(float x) {
    return 1.0f / (1.0f + __expf(-x));
}
__device__ __forceinline__ float tanh_(float x) {
    float e = __expf(-2.0f * fabsf(x));   // (0,1], no overflow
    float r = (1.0f - e) / (1.0f + e);
    return copysignf(r, x);
}

// One block (4 waves) per batch row; lane = hidden unit. The K dimension of
// the gate GEMV ([h (32 f16-pairs) ; x (11 pairs + 5 zero-pad)] = 48 pairs)
// is SPLIT across the 4 waves (12 pairs each) so the per-lane weight
// footprint is 48 VGPRs — small enough that the allocator actually keeps it
// loop-resident (R3/R4: 172-reg footprint was silently refilled every step;
// VGPR_Count=132 < footprint proved it). Per step: 3 ds_read_b128 (B slice),
// 48 fdot2, publish 4 fp32 partials, ONE barrier, gather 3 partners'
// partials, redundant activations in every wave (each wave keeps a PRIVATE
// single-buffered h copy -> h publish is in-wave, no second barrier).
// Partials double-buffered. 2 waves/SIMD of TLP.
__global__ __launch_bounds__(256, 2) void lstm_splitk(
    const float* __restrict__ x,     // [B, C, T]
    const float* __restrict__ W_ih,  // [4H, C]
    const float* __restrict__ W_hh,  // [4H, H]
    const float* __restrict__ b_ih,  // [4H]
    const float* __restrict__ b_hh,  // [4H]
    const float* __restrict__ W_fc,  // [NCLS, T*H]
    const float* __restrict__ b_fc,  // [NCLS]
    float* __restrict__ out)         // [B, NCLS]
{
    __shared__ __align__(16) unsigned xs[TC * 16];   // 16 KB: x chunk, 16 f16-pairs/step
    __shared__ __align__(16) f16 hb[4][HH];          // 512 B: per-wave private h copy
    __shared__ float pbf[2][NCLS][4][HH];            // 8 KB: partials [buf][gate][wave][lane]

    const int tid  = threadIdx.x;
    const int w    = tid >> 6;       // wave id = K-slice id
    const int lane = tid & 63;       // hidden unit
    const int r    = blockIdx.x;     // batch row

    // ---- one-time: per-lane weight slice (48 regs) + bias (wave0 only) ----
    // combined pair index s = 12*w + i : s<32 -> h pair s ; s>=32 -> x pair s-32
    unsigned wgt[4][12];
    float bias0 = 0.f, bias1 = 0.f, bias2 = 0.f, bias3 = 0.f;
    #pragma unroll
    for (int g = 0; g < 4; ++g) {
        const int row = g * HH + lane;
        #pragma unroll
        for (int i = 0; i < 12; ++i) {
            const int s = 12 * w + i;
            float lo, hi;
            if (s < 32) {
                lo = W_hh[row * HH + 2 * s];
                hi = W_hh[row * HH + 2 * s + 1];
            } else {
                const int c0 = 2 * (s - 32);
                lo = (c0     < CC) ? W_ih[row * CC + c0]     : 0.f;
                hi = (c0 + 1 < CC) ? W_ih[row * CC + c0 + 1] : 0.f;
            }
            PU pu; pu.h = h2{(f16)lo, (f16)hi};
            wgt[g][i] = pu.u;
        }
    }
    if (w == 0) {   // bias folded into wave0's partial (counted exactly once)
        bias0 = b_ih[0 * HH + lane] + b_hh[0 * HH + lane];
        bias1 = b_ih[1 * HH + lane] + b_hh[1 * HH + lane];
        bias2 = b_ih[2 * HH + lane] + b_hh[2 * HH + lane];
        bias3 = b_ih[3 * HH + lane] + b_hh[3 * HH + lane];
    }

    hb[w][lane] = (f16)0.0f;         // own-wave copy; in-wave ordering suffices
    float c = 0.0f;
    float fc0 = 0.f, fc1 = 0.f, fc2 = 0.f, fc3 = 0.f;
    const float* xrow = x + (size_t)r * (CC * TT);
    int p = 0;

    for (int chunk = 0; chunk < NCHUNK; ++chunk) {
        // ---- stage x chunk: 16 f16-pairs per step (11 real + 5 zero) ----
        for (int t = tid; t < TC; t += 256) {
            const float* gx = xrow + chunk * TC + t;   // channel stride TT
            unsigned q[16];
            #pragma unroll
            for (int k = 0; k < 16; ++k) {
                const int c0 = 2 * k, c1 = 2 * k + 1;
                float lo = (c0 < CC) ? gx[c0 * TT] : 0.f;
                float hi = (c1 < CC) ? gx[c1 * TT] : 0.f;
                PU pu; pu.h = h2{(f16)lo, (f16)hi};
                q[k] = pu.u;
            }
            uint4* dst = (uint4*)&xs[t * 16];
            dst[0] = *(uint4*)&q[0];  dst[1] = *(uint4*)&q[4];
            dst[2] = *(uint4*)&q[8];  dst[3] = *(uint4*)&q[12];
        }
        __syncthreads();

        for (int tt = 0; tt < TC; ++tt) {
            const int t = chunk * TC + tt;

            // ---- B slice: 12 pairs from own h copy and/or x chunk ----
            union { uint4 q[3]; unsigned u[12]; } Bv;
            const uint4* hq = (const uint4*)&hb[w][0];   // 8 x uint4
            const uint4* xq = (const uint4*)&xs[tt * 16];
            if      (w == 0) { Bv.q[0] = hq[0]; Bv.q[1] = hq[1]; Bv.q[2] = hq[2]; }
            else if (w == 1) { Bv.q[0] = hq[3]; Bv.q[1] = hq[4]; Bv.q[2] = hq[5]; }
            else if (w == 2) { Bv.q[0] = hq[6]; Bv.q[1] = hq[7]; Bv.q[2] = xq[0]; }
            else             { Bv.q[0] = xq[1]; Bv.q[1] = xq[2]; Bv.q[2] = xq[3]; }

            // FC weights for this step (wave0 only; issued before the dots)
            float wv0 = 0.f, wv1 = 0.f, wv2 = 0.f, wv3 = 0.f;
            if (w == 0) {
                const float* pf = W_fc + t * HH + lane;
                wv0 = pf[0];
                wv1 = pf[TT * HH];
                wv2 = pf[2 * TT * HH];
                wv3 = pf[3 * TT * HH];
            }

            // ---- 48 fdot2: 4 gates x 12 pairs (4 independent chains) ----
            float a0 = bias0, a1 = bias1, a2 = bias2, a3 = bias3;
            #pragma unroll
            for (int i = 0; i < 12; ++i) {
                PU b;  b.u  = Bv.u[i];
                PU g0; g0.u = wgt[0][i];
                PU g1; g1.u = wgt[1][i];
                PU g2; g2.u = wgt[2][i];
                PU g3; g3.u = wgt[3][i];
                a0 = __builtin_amdgcn_fdot2(b.h, g0.h, a0, false);
                a1 = __builtin_amdgcn_fdot2(b.h, g1.h, a1, false);
                a2 = __builtin_amdgcn_fdot2(b.h, g2.h, a2, false);
                a3 = __builtin_amdgcn_fdot2(b.h, g3.h, a3, false);
            }

            // ---- publish partials (b32, 2 lanes/bank = conflict-free) ----
            pbf[p][0][w][lane] = a0;
            pbf[p][1][w][lane] = a1;
            pbf[p][2][w][lane] = a2;
            pbf[p][3][w][lane] = a3;
            __syncthreads();   // the ONE per-step barrier

            // ---- gather the other 3 waves' partials ----
            const int wa = (w + 1) & 3, wb = (w + 2) & 3, wc = (w + 3) & 3;
            float r00 = pbf[p][0][wa][lane], r01 = pbf[p][0][wb][lane], r02 = pbf[p][0][wc][lane];
            float r10 = pbf[p][1][wa][lane], r11 = pbf[p][1][wb][lane], r12 = pbf[p][1][wc][lane];
            float r20 = pbf[p][2][wa][lane], r21 = pbf[p][2][wb][lane], r22 = pbf[p][2][wc][lane];
            float r30 = pbf[p][3][wa][lane], r31 = pbf[p][3][wb][lane], r32 = pbf[p][3][wc][lane];
            a0 += (r00 + r01) + r02;
            a1 += (r10 + r11) + r12;
            a2 += (r20 + r21) + r22;
            a3 += (r30 + r31) + r32;

            // ---- redundant lane-local LSTM update (every wave) ----
            float iv = sigm(a0), fv = sigm(a1), gv = tanh_(a2), ov = sigm(a3);
            c = fv * c + iv * gv;
            float h = ov * tanh_(c);

            if (w == 0) {   // fused FC on exact fp32 h
                fc0 += h * wv0; fc1 += h * wv1; fc2 += h * wv2; fc3 += h * wv3;
            }

            // own-copy h publish: in-wave LDS, single buffer is safe
            hb[w][lane] = (f16)h;
            p ^= 1;
        }
    }

    // ---- FC reduce over hid + softmax (wave0 only) ----
    if (w == 0) {
        #pragma unroll
        for (int off = 32; off; off >>= 1) {
            fc0 += __shfl_down(fc0, off);
            fc1 += __shfl_down(fc1, off);
            fc2 += __shfl_down(fc2, off);
            fc3 += __shfl_down(fc3, off);
        }
        if (lane == 0) {
            float l0 = fc0 + b_fc[0], l1 = fc1 + b_fc[1];
            float l2 = fc2 + b_fc[2], l3 = fc3 + b_fc[3];
            float m  = fmaxf(fmaxf(l0, l1), fmaxf(l2, l3));
            float e0 = __expf(l0 - m), e1 = __expf(l1 - m);
            float e2 = __expf(l2 - m), e3 = __expf(l3 - m);
            float s  = e0 + e1 + e2 + e3;
            float4 o; o.x = e0 / s; o.y = e1 / s; o.z = e2 / s; o.w = e3 / s;
            *(float4*)(out + r * NCLS) = o;
        }
    }
}

extern "C" void kernel_launch(void* const* d_in, const int* in_sizes, int n_in,
                              void* d_out, int out_size, void* d_ws, size_t ws_size,
                              hipStream_t stream) {
    const float* x    = (const float*)d_in[0];
    const float* W_ih = (const float*)d_in[1];
    const float* W_hh = (const float*)d_in[2];
    const float* b_ih = (const float*)d_in[3];
    const float* b_hh = (const float*)d_in[4];
    const float* W_fc = (const float*)d_in[5];
    const float* b_fc = (const float*)d_in[6];
    float* out = (float*)d_out;

    lstm_splitk<<<BB, 256, 0, stream>>>(x, W_ih, W_hh, b_ih, b_hh, W_fc, b_fc, out);
}

// Round 6
// 696.701 us; speedup vs baseline: 1.4509x; 1.4509x over previous
//
#include <hip/hip_runtime.h>

// Problem constants
#define BB   512
#define CC   22
#define TT   1000
#define HH   64
#define NCLS 4
#define TC   250          // time chunk staged in LDS
#define NCHUNK (TT / TC)
#define XROW 12           // h2 slots per xs row (11 used, 48B rows, 16B aligned)

typedef _Float16 f16;
typedef __attribute__((ext_vector_type(2))) _Float16 h2;

__device__ __forceinline__ float sigm(float x) {
    return 1.0f / (1.0f + __expf(-x));
}
__device__ __forceinline__ float tanh_(float x) {
    float e = __expf(-2.0f * fabsf(x));   // (0,1], no overflow
    float r = (1.0f - e) / (1.0f + e);
    return copysignf(r, x);
}

__device__ __forceinline__ h2 u2h(unsigned u) {
    union { unsigned u; h2 h; } c; c.u = u; return c.h;
}
__device__ __forceinline__ unsigned h2u(h2 h) {
    union { unsigned u; h2 h; } c; c.h = h; return c.u;
}

// One wave per batch row; lane = hidden unit; each lane computes all 4 gates
// for its hid via v_dot2_f32_f16. Zero barriers: the only cross-lane dep is
// the h broadcast through own-wave LDS (in-order DS pipe) — measured: any
// per-step cross-wave barrier costs ~1000 cyc (R2/R5).
// R6 fix: amdgpu_waves_per_eu(1,1) (min AND max) removes the scheduler's
// occupancy incentive, so the 172-reg weight cache is actually loop-resident.
// R3/R4 evidence: __launch_bounds__(64,1) only sets the MINIMUM waves/EU, and
// the scheduler chose 132 regs (3 waves/SIMD) + per-step weight refills.
__global__
__attribute__((amdgpu_flat_work_group_size(64, 64), amdgpu_waves_per_eu(1, 1)))
void lstm_wave(
    const float* __restrict__ x,     // [B, C, T]
    const float* __restrict__ W_ih,  // [4H, C]
    const float* __restrict__ W_hh,  // [4H, H]
    const float* __restrict__ b_ih,  // [4H]
    const float* __restrict__ b_hh,  // [4H]
    const float* __restrict__ W_fc,  // [NCLS, T*H]
    const float* __restrict__ b_fc,  // [NCLS]
    float* __restrict__ out)         // [B, NCLS]
{
    __shared__ __align__(16) h2  xs[TC][XROW];   // 12 KB: x chunk, f16 pairs
    __shared__ __align__(16) f16 hbuf[HH];       // 128 B: h broadcast buffer

    const int lane = threadIdx.x;    // hidden unit
    const int r    = blockIdx.x;     // batch row

    // ---- per-lane weights into registers (one-time) ----
    unsigned whh[4][32];      // W_hh rows (f16 pairs) for gates i,f,g,o: 128 VGPR
    unsigned wih[4][11];      // W_ih rows: 44 VGPR
    float bias[4];
    #pragma unroll
    for (int g = 0; g < 4; ++g) {
        const int row = g * HH + lane;
        const float* wr = W_hh + row * HH;
        #pragma unroll
        for (int k = 0; k < 32; ++k)
            whh[g][k] = h2u(h2{(f16)wr[2 * k], (f16)wr[2 * k + 1]});
        const float* wi = W_ih + row * CC;
        #pragma unroll
        for (int k = 0; k < 11; ++k)
            wih[g][k] = h2u(h2{(f16)wi[2 * k], (f16)wi[2 * k + 1]});
        bias[g] = b_ih[row] + b_hh[row];
    }

    hbuf[lane] = (f16)0.0f;          // in-wave ordering; no barrier needed
    float c = 0.0f;
    float fc0 = 0.f, fc1 = 0.f, fc2 = 0.f, fc3 = 0.f;
    const float* p0 = W_fc + 0 * (TT * HH) + lane;
    const float* p1 = W_fc + 1 * (TT * HH) + lane;
    const float* p2 = W_fc + 2 * (TT * HH) + lane;
    const float* p3 = W_fc + 3 * (TT * HH) + lane;
    const float* xrow = x + (size_t)r * (CC * TT);

    for (int chunk = 0; chunk < NCHUNK; ++chunk) {
        // ---- stage own row's x chunk into LDS as f16 pairs (off-chain) ----
        for (int tb = 0; tb < TC; tb += 64) {
            const int t = tb + lane;
            if (t < TC) {
                const float* gx = xrow + chunk * TC + t;   // stride TT between channels
                union { h2 h[XROW]; uint4 q[3]; } U;
                #pragma unroll
                for (int k = 0; k < 11; ++k)
                    U.h[k] = h2{(f16)gx[(2 * k) * TT], (f16)gx[(2 * k + 1) * TT]};
                U.h[11] = h2{(f16)0.0f, (f16)0.0f};
                uint4* dst = (uint4*)&xs[t][0];
                dst[0] = U.q[0]; dst[1] = U.q[1]; dst[2] = U.q[2];
            }
        }
        // no __syncthreads: xs is own-wave data, DS ops are in-order per wave

        for (int tt = 0; tt < TC; ++tt) {
            // h broadcast (8 x ds_read_b128, all lanes same address)
            union { uint4 q[8]; h2 h[32]; } H;
            const uint4* hr = (const uint4*)hbuf;
            #pragma unroll
            for (int i = 0; i < 8; ++i) H.q[i] = hr[i];

            // x broadcast (3 x ds_read_b128)
            union { uint4 q[3]; h2 h[XROW]; } X;
            const uint4* xr = (const uint4*)&xs[tt][0];
            X.q[0] = xr[0]; X.q[1] = xr[1]; X.q[2] = xr[2];

            // W_fc for this step (global, no barrier -> latency hidden)
            float w0 = *p0, w1 = *p1, w2 = *p2, w3 = *p3;
            p0 += HH; p1 += HH; p2 += HH; p3 += HH;

            // 4 gate dots: x part first (independent of h read), then h part
            float a0 = bias[0], a1 = bias[1], a2 = bias[2], a3 = bias[3];
            #pragma unroll
            for (int k = 0; k < 11; ++k) {
                a0 = __builtin_amdgcn_fdot2(X.h[k], u2h(wih[0][k]), a0, false);
                a1 = __builtin_amdgcn_fdot2(X.h[k], u2h(wih[1][k]), a1, false);
                a2 = __builtin_amdgcn_fdot2(X.h[k], u2h(wih[2][k]), a2, false);
                a3 = __builtin_amdgcn_fdot2(X.h[k], u2h(wih[3][k]), a3, false);
            }
            #pragma unroll
            for (int k = 0; k < 32; ++k) {
                a0 = __builtin_amdgcn_fdot2(H.h[k], u2h(whh[0][k]), a0, false);
                a1 = __builtin_amdgcn_fdot2(H.h[k], u2h(whh[1][k]), a1, false);
                a2 = __builtin_amdgcn_fdot2(H.h[k], u2h(whh[2][k]), a2, false);
                a3 = __builtin_amdgcn_fdot2(H.h[k], u2h(whh[3][k]), a3, false);
            }

            // lane-local LSTM update
            float iv = sigm(a0), fv = sigm(a1), gv = tanh_(a2), ov = sigm(a3);
            c = fv * c + iv * gv;
            float h = ov * tanh_(c);

            // fused FC accumulation (fp32 h, fp32 W_fc)
            fc0 += h * w0; fc1 += h * w1; fc2 += h * w2; fc3 += h * w3;

            // publish h for next step (in-wave LDS, single buffer is safe:
            // this step's reads completed before this write issues)
            hbuf[lane] = (f16)h;
        }
    }

    // ---- FC reduce over hid (wave shuffle) + softmax ----
    #pragma unroll
    for (int off = 32; off; off >>= 1) {
        fc0 += __shfl_down(fc0, off);
        fc1 += __shfl_down(fc1, off);
        fc2 += __shfl_down(fc2, off);
        fc3 += __shfl_down(fc3, off);
    }
    if (lane == 0) {
        float l0 = fc0 + b_fc[0], l1 = fc1 + b_fc[1];
        float l2 = fc2 + b_fc[2], l3 = fc3 + b_fc[3];
        float m  = fmaxf(fmaxf(l0, l1), fmaxf(l2, l3));
        float e0 = __expf(l0 - m), e1 = __expf(l1 - m);
        float e2 = __expf(l2 - m), e3 = __expf(l3 - m);
        float s  = e0 + e1 + e2 + e3;
        float4 o; o.x = e0 / s; o.y = e1 / s; o.z = e2 / s; o.w = e3 / s;
        *(float4*)(out + r * NCLS) = o;
    }
}

extern "C" void kernel_launch(void* const* d_in, const int* in_sizes, int n_in,
                              void* d_out, int out_size, void* d_ws, size_t ws_size,
                              hipStream_t stream) {
    const float* x    = (const float*)d_in[0];
    const float* W_ih = (const float*)d_in[1];
    const float* W_hh = (const float*)d_in[2];
    const float* b_ih = (const float*)d_in[3];
    const float* b_hh = (const float*)d_in[4];
    const float* W_fc = (const float*)d_in[5];
    const float* b_fc = (const float*)d_in[6];
    float* out = (float*)d_out;

    lstm_wave<<<BB, 64, 0, stream>>>(x, W_ih, W_hh, b_ih, b_hh, W_fc, b_fc, out);
}